// Round 7
// baseline (183.413 us; speedup 1.0000x reference)
//
#include <hip/hip_runtime.h>

#define IN_F    4096
#define OUT_F   4096
#define K_DIM   4096
#define NNZ_C   838860
#define BATCH   512
#define SPLITK  8
#define KS      (K_DIM / SPLITK)   // 512 per split -> 8 k-iters of BK=64
#define BK      64
#define BM      128
#define BN      128

typedef short bf16x8 __attribute__((ext_vector_type(8)));
typedef float f32x4  __attribute__((ext_vector_type(4)));

__device__ __forceinline__ unsigned short f2bf(float f) {  // RNE fp32->bf16
    unsigned u = __float_as_uint(f);
    u += 0x7fffu + ((u >> 16) & 1u);
    return (unsigned short)(u >> 16);
}
__device__ __forceinline__ void gload_lds16(const void* g, void* l) {
    __builtin_amdgcn_global_load_lds(
        (const __attribute__((address_space(1))) unsigned int*)g,
        (__attribute__((address_space(3))) unsigned int*)l, 16, 0, 0);
}

// ---------------------------------------------------------------------------
// K1 "prep": fused  (a) zero W (33.5 MB),  (b) x fp32->bf16,  (c) out = bias.
// One launch instead of three; all ranges are multiples of 64 so branches
// are wave-uniform. Must precede scatter (a) and gemm (b,c).
// ---------------------------------------------------------------------------
#define N_WZ   (OUT_F * K_DIM / 8)       // 2097152 uint4 stores
#define N_CVT  (BATCH * K_DIM / 8)       // 262144 bf16x8 outputs
#define N_OUT  (BATCH * OUT_F / 4)       // 524288 float4 stores
__global__ void prep(const float* __restrict__ x,
                     unsigned short* __restrict__ xb,
                     const float* __restrict__ bias,
                     float* __restrict__ out,
                     uint4* __restrict__ Wz) {
    int i = blockIdx.x * 256 + threadIdx.x;
    if (i < N_WZ) { Wz[i] = make_uint4(0, 0, 0, 0); return; }
    i -= N_WZ;
    if (i < N_CVT) {
        const float4* p = (const float4*)x + (size_t)i * 2;
        float4 a = p[0], b = p[1];
        union { unsigned short h[8]; bf16x8 v; } u;
        u.h[0] = f2bf(a.x); u.h[1] = f2bf(a.y); u.h[2] = f2bf(a.z); u.h[3] = f2bf(a.w);
        u.h[4] = f2bf(b.x); u.h[5] = f2bf(b.y); u.h[6] = f2bf(b.z); u.h[7] = f2bf(b.w);
        ((bf16x8*)xb)[i] = u.v;
        return;
    }
    i -= N_CVT;
    if (i < N_OUT) {
        float4 b = ((const float4*)bias)[i & (OUT_F / 4 - 1)];
        ((float4*)out)[i] = b;
    }
}
#define PREP_BLOCKS ((N_WZ + N_CVT + N_OUT) / 256)

// ---------------------------------------------------------------------------
// K2: COO scatter-add via packed-bf16 atomic fadd (fire-and-forget, exact
// duplicate handling, no CAS, no returning atomics -- R4 lesson).
// ---------------------------------------------------------------------------
__global__ void scatter_pk(const int* __restrict__ row_idx,
                           const int* __restrict__ col_idx,
                           const float* __restrict__ values,
                           unsigned short* __restrict__ W) {
    int i = blockIdx.x * 256 + threadIdx.x;
    if (i >= NNZ_C) return;
    unsigned idx = (unsigned)row_idx[i] * K_DIM + (unsigned)col_idx[i];
    unsigned short h = f2bf(values[i]);
    unsigned data = (idx & 1u) ? ((unsigned)h << 16) : (unsigned)h;
    unsigned long long addr = (unsigned long long)(W + (idx & ~1u));
    asm volatile("global_atomic_pk_add_bf16 %0, %1, off"
                 :: "v"(addr), "v"(data) : "memory");
}

// ---------------------------------------------------------------------------
// K3: bf16 GEMM, B^T layout, 128x128 tile, BK=64, split-K=8.
//   - 1024 blocks -> 4 blocks/CU, 16 waves/CU (R6 was 2 blocks/CU, the
//     diagnosed barrier-stall bottleneck); BK=64 halves barrier count.
//   - LDS row = 64 bf16 = 128 B = 8 x 16B chunks. Row stride is exactly 32
//     banks, so unswizzled reads would be 16-way conflicted. XOR swizzle:
//     phys chunk p of row r holds logical chunk p ^ (r&7). Staged with a
//     lane-id-only source swizzle (gload LDS dst is HW lane-linear); read
//     side: 16 lanes (lanem) x phys=(l^lanem&7) covers all 32 banks 2x =
//     conflict-free (m136: 2-way is free). Row bases are multiples of 8,
//     so r&7 reduces to lane bits on both sides.
//   - Epilogue: returnless atomicAdd f32 into bias-initialized out.
// ---------------------------------------------------------------------------
__global__ void __launch_bounds__(256)
gemm_bt(const unsigned short* __restrict__ Abf,   // [512][4096] bf16
        const unsigned short* __restrict__ Wbf,   // [4096][4096] bf16
        float* __restrict__ out) {                // [512][4096] f32, bias-filled
    __shared__ __align__(16) unsigned short As[BM * BK];   // 16 KB
    __shared__ __align__(16) unsigned short Bs[BN * BK];   // 16 KB

    const int nt = blockIdx.x, mt = blockIdx.y, s = blockIdx.z;
    const int t = threadIdx.x, w = t >> 6, ln = t & 63;
    const int wm = w & 1, wn = w >> 1;
    const int ks0 = s * KS;

    // staging: wave w covers rows [32w, 32w+32) of As and Bs, 4 groups of 8
    // rows. lane ln -> row +(ln>>3), phys chunk (ln&7);
    // logical (global) chunk = (ln&7) ^ ((ln>>3)&7).
    const int r_in  = ln >> 3;                       // 0..7
    const int lchk  = (ln & 7) ^ r_in;
    const int scol  = lchk * 8;                      // bf16 elems
    const int srow  = 32 * w + r_in;
    const unsigned short* gA = Abf + (size_t)(mt * BM + srow) * K_DIM + ks0 + scol;
    const unsigned short* gB = Wbf + (size_t)(nt * BN + srow) * K_DIM + ks0 + scol;
    unsigned short* lA = &As[(32 * w) * BK];
    unsigned short* lB = &Bs[(32 * w) * BK];

    const int quad = ln >> 4, lanem = ln & 15;
    const int lm7 = lanem & 7;

    f32x4 acc[4][4];
#pragma unroll
    for (int mi = 0; mi < 4; ++mi)
#pragma unroll
        for (int ni = 0; ni < 4; ++ni)
            acc[mi][ni] = (f32x4){0.f, 0.f, 0.f, 0.f};

    for (int kt = 0; kt < KS / BK; ++kt) {           // 8 iters
        __syncthreads();
#pragma unroll
        for (int j = 0; j < 4; ++j) {
            gload_lds16(gA + (size_t)(8 * j) * K_DIM + kt * BK, lA + (8 * j) * BK);
            gload_lds16(gB + (size_t)(8 * j) * K_DIM + kt * BK, lB + (8 * j) * BK);
        }
        __syncthreads();

#pragma unroll
        for (int kh = 0; kh < 2; ++kh) {             // two K=32 halves
            bf16x8 af[4], bfr[4];
#pragma unroll
            for (int mi = 0; mi < 4; ++mi) {
                int row = wm * 64 + mi * 16 + lanem;
                int phys = (kh * 4 + quad) ^ lm7;
                af[mi] = *(const bf16x8*)&As[row * BK + phys * 8];
            }
#pragma unroll
            for (int ni = 0; ni < 4; ++ni) {
                int row = wn * 64 + ni * 16 + lanem;
                int phys = (kh * 4 + quad) ^ lm7;
                bfr[ni] = *(const bf16x8*)&Bs[row * BK + phys * 8];
            }
#pragma unroll
            for (int mi = 0; mi < 4; ++mi)
#pragma unroll
                for (int ni = 0; ni < 4; ++ni)
                    acc[mi][ni] = __builtin_amdgcn_mfma_f32_16x16x32_bf16(
                        af[mi], bfr[ni], acc[mi][ni], 0, 0, 0);
        }
    }

    // C/D layout: col = lanem, row = quad*4 + r. Returnless atomicAdd,
    // 16 consecutive lanes per 64B segment.
    const int row0 = mt * BM + wm * 64 + quad * 4;
    const int col0 = nt * BN + wn * 64 + lanem;
#pragma unroll
    for (int mi = 0; mi < 4; ++mi)
#pragma unroll
        for (int ni = 0; ni < 4; ++ni) {
            int c = col0 + ni * 16;
#pragma unroll
            for (int r = 0; r < 4; ++r) {
                size_t o = (size_t)(row0 + mi * 16 + r) * OUT_F + c;
                atomicAdd(&out[o], acc[mi][ni][r]);
            }
        }
}

// ---------------------------------------------------------------------------
// ws: xb 4.19 MB | W 33.55 MB  = 37.75 MB total
// ---------------------------------------------------------------------------
extern "C" void kernel_launch(void* const* d_in, const int* in_sizes, int n_in,
                              void* d_out, int out_size, void* d_ws, size_t ws_size,
                              hipStream_t stream) {
    const float* x       = (const float*)d_in[0];
    const int*   row_idx = (const int*)d_in[1];
    const int*   col_idx = (const int*)d_in[2];
    const float* values  = (const float*)d_in[3];
    const float* bias    = (const float*)d_in[4];
    float*       out     = (float*)d_out;

    unsigned short* xb = (unsigned short*)d_ws;
    unsigned short* W  = xb + (size_t)BATCH * K_DIM;

    prep<<<PREP_BLOCKS, 256, 0, stream>>>(x, xb, bias, out, (uint4*)W);
    scatter_pk<<<(NNZ_C + 255) / 256, 256, 0, stream>>>(row_idx, col_idx, values, W);
    gemm_bt<<<dim3(OUT_F / BN, BATCH / BM, SPLITK), 256, 0, stream>>>(xb, W, out);
}

// Round 8
// 162.954 us; speedup vs baseline: 1.1256x; 1.1256x over previous
//
#include <hip/hip_runtime.h>

#define IN_F    4096
#define OUT_F   4096
#define K_DIM   4096
#define NNZ_C   838860
#define BATCH   512
#define BK      32
#define BM      128
#define BN      128

typedef short bf16x8 __attribute__((ext_vector_type(8)));
typedef float f32x4  __attribute__((ext_vector_type(4)));

__device__ __forceinline__ unsigned short f2bf(float f) {  // RNE fp32->bf16
    unsigned u = __float_as_uint(f);
    u += 0x7fffu + ((u >> 16) & 1u);
    return (unsigned short)(u >> 16);
}
__device__ __forceinline__ void gload_lds16(const void* g, void* l) {
    __builtin_amdgcn_global_load_lds(
        (const __attribute__((address_space(1))) unsigned int*)g,
        (__attribute__((address_space(3))) unsigned int*)l, 16, 0, 0);
}

// ---------------------------------------------------------------------------
// K1 "prep": (a) zero W, (b) x fp32->bf16, (c) optional out=bias (fallback
// path only; parts path writes bias in the gemm's split-0 store).
// ---------------------------------------------------------------------------
#define N_WZ   (OUT_F * K_DIM / 8)       // uint4 stores
#define N_CVT  (BATCH * K_DIM / 8)       // bf16x8 outputs
#define N_OUT  (BATCH * OUT_F / 4)       // float4 stores
__global__ void prep(const float* __restrict__ x,
                     unsigned short* __restrict__ xb,
                     const float* __restrict__ bias,
                     float* __restrict__ out,
                     uint4* __restrict__ Wz, int do_bias) {
    int i = blockIdx.x * 256 + threadIdx.x;
    if (i < N_WZ) { Wz[i] = make_uint4(0, 0, 0, 0); return; }
    i -= N_WZ;
    if (i < N_CVT) {
        const float4* p = (const float4*)x + (size_t)i * 2;
        float4 a = p[0], b = p[1];
        union { unsigned short h[8]; bf16x8 v; } u;
        u.h[0] = f2bf(a.x); u.h[1] = f2bf(a.y); u.h[2] = f2bf(a.z); u.h[3] = f2bf(a.w);
        u.h[4] = f2bf(b.x); u.h[5] = f2bf(b.y); u.h[6] = f2bf(b.z); u.h[7] = f2bf(b.w);
        ((bf16x8*)xb)[i] = u.v;
        return;
    }
    i -= N_CVT;
    if (i < N_OUT && do_bias) {
        float4 b = ((const float4*)bias)[i & (OUT_F / 4 - 1)];
        ((float4*)out)[i] = b;
    }
}
#define PREP_BLOCKS ((N_WZ + N_CVT + N_OUT) / 256)

// ---------------------------------------------------------------------------
// K2: COO scatter-add, 4 entries/thread (int4/float4 loads), fire-and-forget
// packed-bf16 atomic fadd (exact duplicate handling, no returns -- R4 lesson).
// ---------------------------------------------------------------------------
__global__ void scatter_pk(const int* __restrict__ row_idx,
                           const int* __restrict__ col_idx,
                           const float* __restrict__ values,
                           unsigned short* __restrict__ W) {
    int i = blockIdx.x * 256 + threadIdx.x;          // NNZ_C/4 = 209715 exact
    if (i >= NNZ_C / 4) return;
    int4   r4 = ((const int4*)row_idx)[i];
    int4   c4 = ((const int4*)col_idx)[i];
    float4 v4 = ((const float4*)values)[i];
#pragma unroll
    for (int j = 0; j < 4; ++j) {
        int r = (&r4.x)[j], c = (&c4.x)[j];
        float v = (&v4.x)[j];
        unsigned idx = (unsigned)r * K_DIM + (unsigned)c;
        unsigned short h = f2bf(v);
        unsigned data = (idx & 1u) ? ((unsigned)h << 16) : (unsigned)h;
        unsigned long long addr = (unsigned long long)(W + (idx & ~1u));
        asm volatile("global_atomic_pk_add_bf16 %0, %1, off"
                     :: "v"(addr), "v"(data) : "memory");
    }
}

// ---------------------------------------------------------------------------
// K3: bf16 GEMM, B^T layout, 128x128xBK32, R6's conflict-free XOR swizzle
// (verbatim). Template: SK = split-K factor; EPI 0 = plain-store epilogue
// (s==0 -> out with bias, s>0 -> parts[s-1]); EPI 1 = atomicAdd fallback.
// SK=8 -> 1024 blocks = 4/CU (R6 diagnosis: 2/CU was barrier-stall-bound).
// ---------------------------------------------------------------------------
template <int EPI, int SK>
__global__ void __launch_bounds__(256)
gemm_bt(const unsigned short* __restrict__ Abf,   // [512][4096] bf16
        const unsigned short* __restrict__ Wbf,   // [4096][4096] bf16
        const float* __restrict__ bias,
        float* __restrict__ out,                  // [512][4096] f32
        float* __restrict__ parts) {              // (SK-1) x [512][4096] f32
    __shared__ __align__(16) unsigned short As[BM * BK];   // 8 KB
    __shared__ __align__(16) unsigned short Bs[BN * BK];   // 8 KB

    const int nt = blockIdx.x, mt = blockIdx.y, s = blockIdx.z;
    const int t = threadIdx.x, w = t >> 6, ln = t & 63;
    const int wm = w & 1, wn = w >> 1;
    const int KSs = K_DIM / SK;
    const int ks0 = s * KSs;

    // staging: lane ln -> LDS row (ln>>2), physical chunk (ln&3);
    // global source = logical chunk (ln&3) ^ ((ln>>3)&3)   [R6: 0 conflicts]
    const int srow = w * 16 + (ln >> 2);
    const int scol = (((ln & 3) ^ ((ln >> 3) & 3)) * 8);
    const unsigned short* gA0 = Abf + (size_t)(mt * BM + srow) * K_DIM + ks0 + scol;
    const unsigned short* gA1 = gA0 + (size_t)64 * K_DIM;
    const unsigned short* gB0 = Wbf + (size_t)(nt * BN + srow) * K_DIM + ks0 + scol;
    const unsigned short* gB1 = gB0 + (size_t)64 * K_DIM;
    unsigned short* lA0 = &As[(w * 16) * BK];
    unsigned short* lA1 = &As[(64 + w * 16) * BK];
    unsigned short* lB0 = &Bs[(w * 16) * BK];
    unsigned short* lB1 = &Bs[(64 + w * 16) * BK];

    // read: logical quad q -> physical chunk q ^ ((lanem>>1)&3)
    const int quad = ln >> 4, lanem = ln & 15;
    const int rsw = (quad ^ ((lanem >> 1) & 3)) * 8;
    const unsigned short* rA = &As[(wm * 64 + lanem) * BK + rsw];
    const unsigned short* rB = &Bs[(wn * 64 + lanem) * BK + rsw];

    f32x4 acc[4][4];
#pragma unroll
    for (int mi = 0; mi < 4; ++mi)
#pragma unroll
        for (int ni = 0; ni < 4; ++ni)
            acc[mi][ni] = (f32x4){0.f, 0.f, 0.f, 0.f};

    for (int kt = 0; kt < KSs / BK; ++kt) {
        __syncthreads();
        gload_lds16(gA0 + kt * BK, lA0);
        gload_lds16(gA1 + kt * BK, lA1);
        gload_lds16(gB0 + kt * BK, lB0);
        gload_lds16(gB1 + kt * BK, lB1);
        __syncthreads();

        bf16x8 af[4], bfr[4];
#pragma unroll
        for (int mi = 0; mi < 4; ++mi) af[mi]  = *(const bf16x8*)(rA + mi * 16 * BK);
#pragma unroll
        for (int ni = 0; ni < 4; ++ni) bfr[ni] = *(const bf16x8*)(rB + ni * 16 * BK);
#pragma unroll
        for (int mi = 0; mi < 4; ++mi)
#pragma unroll
            for (int ni = 0; ni < 4; ++ni)
                acc[mi][ni] = __builtin_amdgcn_mfma_f32_16x16x32_bf16(
                    af[mi], bfr[ni], acc[mi][ni], 0, 0, 0);
    }

    // C/D layout: col = lanem, row = quad*4 + r; 16 lanes = one 64B segment.
    const int row0 = mt * BM + wm * 64 + quad * 4;
    const int col0 = nt * BN + wn * 64 + lanem;
    if (EPI == 0) {
        float bv[4];
#pragma unroll
        for (int ni = 0; ni < 4; ++ni) bv[ni] = (s == 0) ? bias[col0 + ni * 16] : 0.f;
        float* dst = (s == 0) ? out : parts + (size_t)(s - 1) * BATCH * OUT_F;
#pragma unroll
        for (int mi = 0; mi < 4; ++mi)
#pragma unroll
            for (int ni = 0; ni < 4; ++ni)
#pragma unroll
                for (int r = 0; r < 4; ++r)
                    dst[(size_t)(row0 + mi * 16 + r) * OUT_F + col0 + ni * 16] =
                        acc[mi][ni][r] + bv[ni];
    } else {
#pragma unroll
        for (int mi = 0; mi < 4; ++mi)
#pragma unroll
            for (int ni = 0; ni < 4; ++ni)
#pragma unroll
                for (int r = 0; r < 4; ++r)
                    atomicAdd(&out[(size_t)(row0 + mi * 16 + r) * OUT_F + col0 + ni * 16],
                              acc[mi][ni][r]);
    }
}

// ---------------------------------------------------------------------------
// K4: out += sum(parts[0..6])  (75 MB streamed, ~13 us)
// ---------------------------------------------------------------------------
__global__ void reduce_parts(float* __restrict__ out,
                             const float* __restrict__ parts) {
    int i = blockIdx.x * 256 + threadIdx.x;          // 524288 float4s
    float4 a = ((const float4*)out)[i];
#pragma unroll
    for (int p = 0; p < 7; ++p) {
        float4 b = ((const float4*)(parts + (size_t)p * BATCH * OUT_F))[i];
        a.x += b.x; a.y += b.y; a.z += b.z; a.w += b.w;
    }
    ((float4*)out)[i] = a;
}

// ---------------------------------------------------------------------------
// ws: xb 4.19 | W 33.55 | parts 7 x 8.39 = 58.72  -> 96.5 MB (fallback if less)
// ---------------------------------------------------------------------------
extern "C" void kernel_launch(void* const* d_in, const int* in_sizes, int n_in,
                              void* d_out, int out_size, void* d_ws, size_t ws_size,
                              hipStream_t stream) {
    const float* x       = (const float*)d_in[0];
    const int*   row_idx = (const int*)d_in[1];
    const int*   col_idx = (const int*)d_in[2];
    const float* values  = (const float*)d_in[3];
    const float* bias    = (const float*)d_in[4];
    float*       out     = (float*)d_out;

    unsigned short* xb = (unsigned short*)d_ws;
    unsigned short* W  = xb + (size_t)BATCH * K_DIM;
    float* parts = (float*)(W + (size_t)OUT_F * K_DIM);
    size_t need = (size_t)BATCH * K_DIM * 2 + (size_t)OUT_F * K_DIM * 2
                + (size_t)7 * BATCH * OUT_F * 4;
    bool use_parts = (ws_size >= need);

    prep<<<PREP_BLOCKS, 256, 0, stream>>>(x, xb, bias, out, (uint4*)W,
                                          use_parts ? 0 : 1);
    scatter_pk<<<(NNZ_C / 4 + 255) / 256, 256, 0, stream>>>(
        row_idx, col_idx, values, W);

    if (use_parts) {
        gemm_bt<0, 8><<<dim3(OUT_F / BN, BATCH / BM, 8), 256, 0, stream>>>(
            xb, W, bias, out, parts);
        reduce_parts<<<BATCH * OUT_F / 4 / 256, 256, 0, stream>>>(out, parts);
    } else {
        gemm_bt<1, 4><<<dim3(OUT_F / BN, BATCH / BM, 4), 256, 0, stream>>>(
            xb, W, bias, out, nullptr);
    }
}